// Round 4
// baseline (1560.170 us; speedup 1.0000x reference)
//
#include <hip/hip_runtime.h>
#include <math.h>

#define NX 2048
#define LY 256
#define NH 24
#define DH 128
#define DXC 3072
#define DYC 1536
#define NLTOK 2304
#define NTOT 2248
#define RMS_EPS 1e-6f

typedef __bf16 bf16x8 __attribute__((ext_vector_type(8)));
typedef float f32x4 __attribute__((ext_vector_type(4)));

static __device__ __forceinline__ unsigned short f2bf(float f) {
    union { float f; unsigned int u; } x; x.f = f;
    unsigned int r = (x.u + 0x7fffu + ((x.u >> 16) & 1u)) >> 16;
    return (unsigned short)r;
}
static __device__ __forceinline__ float bf2f(unsigned short u) {
    union { unsigned int u; float f; } x; x.u = ((unsigned int)u) << 16;
    return x.f;
}
static __device__ __forceinline__ unsigned int pack2(float lo, float hi) {
    return (unsigned int)f2bf(lo) | ((unsigned int)f2bf(hi) << 16);
}
// split fp32 -> hi (truncate) + lo (RN of remainder); residual <= 2^-17 |x|
static __device__ __forceinline__ void split4(float4 f, uint2& h, uint2& l) {
    unsigned int ux = __float_as_uint(f.x), uy = __float_as_uint(f.y);
    unsigned int uz = __float_as_uint(f.z), uw = __float_as_uint(f.w);
    h.x = (ux >> 16) | (uy & 0xffff0000u);
    h.y = (uz >> 16) | (uw & 0xffff0000u);
    float lx = f.x - __uint_as_float(ux & 0xffff0000u);
    float ly = f.y - __uint_as_float(uy & 0xffff0000u);
    float lz = f.z - __uint_as_float(uz & 0xffff0000u);
    float lw = f.w - __uint_as_float(uw & 0xffff0000u);
    l.x = pack2(lx, ly);
    l.y = pack2(lz, lw);
}

// ---------------- rmsnorm * (1 + scale) -> split bf16 hi/lo ----------------
__global__ __launch_bounds__(256) void rmsnorm_scale_split_kernel(
    const float* __restrict__ in, const float* __restrict__ scale,
    unsigned short* __restrict__ out_hi, unsigned short* __restrict__ out_lo,
    int cols)
{
    const int row = blockIdx.x;
    const int tid = threadIdx.x;
    const float* rp = in + (size_t)row * cols;
    const int nv = cols >> 2;
    float4 vals[3];
    float ss = 0.f;
    int cnt = 0;
    for (int c4 = tid; c4 < nv; c4 += 256) {
        float4 v = ((const float4*)rp)[c4];
        vals[cnt++] = v;
        ss += v.x * v.x + v.y * v.y + v.z * v.z + v.w * v.w;
    }
#pragma unroll
    for (int m = 1; m < 64; m <<= 1) ss += __shfl_xor(ss, m, 64);
    __shared__ float red[4];
    if ((tid & 63) == 0) red[tid >> 6] = ss;
    __syncthreads();
    const float tot = red[0] + red[1] + red[2] + red[3];
    const float r = rsqrtf(tot / (float)cols + RMS_EPS);
    unsigned short* oh = out_hi + (size_t)row * cols;
    unsigned short* ol = out_lo + (size_t)row * cols;
    cnt = 0;
    for (int c4 = tid; c4 < nv; c4 += 256) {
        float4 v = vals[cnt++];
        float4 s = ((const float4*)scale)[c4];
        float4 o;
        o.x = v.x * r * (1.f + s.x);
        o.y = v.y * r * (1.f + s.y);
        o.z = v.z * r * (1.f + s.z);
        o.w = v.w * r * (1.f + s.w);
        uint2 h, l;
        split4(o, h, l);
        ((uint2*)oh)[c4] = h;
        ((uint2*)ol)[c4] = l;
    }
}

// ---------------- split-bf16 3-term MFMA GEMM ----------------
// C[m,n] = sum_k A[m,k]*B[n,k] + bias[n]; A pre-split (hi/lo bf16), B fp32
// split in-kernel. mode 0: fp32 C (ld=Nc). mode 1: bf16 scatter to q/k/v.
// B's split4 is hoisted into the MFMA-overlapped prefetch region so the
// inter-barrier section is pure ds_write_b128 (no VALU on critical path).
__global__ __launch_bounds__(256) void gemm_split_kernel(
    const unsigned short* __restrict__ Ahg, const unsigned short* __restrict__ Alg,
    const float* __restrict__ Bg, const float* __restrict__ bias,
    float* __restrict__ C,
    unsigned short* __restrict__ qp, unsigned short* __restrict__ kp,
    unsigned short* __restrict__ vp,
    int Nc, int K, int mode, int row_off)
{
    __shared__ unsigned short Ah[128 * 40];   // rows stride 40 (80B): b128 reads 2-way
    __shared__ unsigned short Al[128 * 40];
    __shared__ unsigned short Bh[128 * 40];
    __shared__ unsigned short Bl[128 * 40];

    const int tid = threadIdx.x;
    const int n0 = blockIdx.x * 128;
    const int m0 = blockIdx.y * 128;
    const int wave = tid >> 6, lane = tid & 63;
    const int quad = lane >> 4, ln = lane & 15;
    const int wm = wave >> 1, wn = wave & 1;
    const int sr = tid >> 1;            // staged row 0..127
    const int sk = (tid & 1) * 16;      // k-half (elements)

    const unsigned short* Abh = Ahg + (size_t)(m0 + sr) * K + sk;
    const unsigned short* Abl = Alg + (size_t)(m0 + sr) * K + sk;
    const float* Bb = Bg + (size_t)(n0 + sr) * K + sk;

    f32x4 acc[4][4];
#pragma unroll
    for (int i = 0; i < 4; ++i)
#pragma unroll
        for (int j = 0; j < 4; ++j) acc[i][j] = (f32x4){0.f, 0.f, 0.f, 0.f};

    // prefetch k0 = 0, pre-split B into register words
    uint4 pah0 = *(const uint4*)Abh;
    uint4 pah1 = *(const uint4*)(Abh + 8);
    uint4 pal0 = *(const uint4*)Abl;
    uint4 pal1 = *(const uint4*)(Abl + 8);
    uint4 pbh0, pbh1, pbl0, pbl1;
    {
        float4 b0 = ((const float4*)Bb)[0];
        float4 b1 = ((const float4*)Bb)[1];
        float4 b2 = ((const float4*)Bb)[2];
        float4 b3 = ((const float4*)Bb)[3];
        uint2 h0, l0, h1, l1, h2, l2, h3, l3;
        split4(b0, h0, l0); split4(b1, h1, l1);
        split4(b2, h2, l2); split4(b3, h3, l3);
        pbh0 = make_uint4(h0.x, h0.y, h1.x, h1.y);
        pbh1 = make_uint4(h2.x, h2.y, h3.x, h3.y);
        pbl0 = make_uint4(l0.x, l0.y, l1.x, l1.y);
        pbl1 = make_uint4(l2.x, l2.y, l3.x, l3.y);
    }

    for (int k0 = 0; k0 < K; k0 += 32) {
        __syncthreads();   // previous fragment reads done
        *(uint4*)&Ah[sr * 40 + sk]     = pah0;
        *(uint4*)&Ah[sr * 40 + sk + 8] = pah1;
        *(uint4*)&Al[sr * 40 + sk]     = pal0;
        *(uint4*)&Al[sr * 40 + sk + 8] = pal1;
        *(uint4*)&Bh[sr * 40 + sk]     = pbh0;
        *(uint4*)&Bh[sr * 40 + sk + 8] = pbh1;
        *(uint4*)&Bl[sr * 40 + sk]     = pbl0;
        *(uint4*)&Bl[sr * 40 + sk + 8] = pbl1;
        __syncthreads();

        if (k0 + 32 < K) {   // prefetch + split next tile (overlaps MFMA below)
            const unsigned short* ah2 = Abh + k0 + 32;
            const unsigned short* al2 = Abl + k0 + 32;
            const float* b2p = Bb + k0 + 32;
            pah0 = *(const uint4*)ah2;  pah1 = *(const uint4*)(ah2 + 8);
            pal0 = *(const uint4*)al2;  pal1 = *(const uint4*)(al2 + 8);
            float4 b0 = ((const float4*)b2p)[0];
            float4 b1 = ((const float4*)b2p)[1];
            float4 b2 = ((const float4*)b2p)[2];
            float4 b3 = ((const float4*)b2p)[3];
            uint2 h0, l0, h1, l1, h2, l2, h3, l3;
            split4(b0, h0, l0); split4(b1, h1, l1);
            split4(b2, h2, l2); split4(b3, h3, l3);
            pbh0 = make_uint4(h0.x, h0.y, h1.x, h1.y);
            pbh1 = make_uint4(h2.x, h2.y, h3.x, h3.y);
            pbl0 = make_uint4(l0.x, l0.y, l1.x, l1.y);
            pbl1 = make_uint4(l2.x, l2.y, l3.x, l3.y);
        }

        bf16x8 afh[4], afl[4];
#pragma unroll
        for (int mt = 0; mt < 4; ++mt) {
            const int rr = (wm * 64 + mt * 16 + ln) * 40 + quad * 8;
            afh[mt] = __builtin_bit_cast(bf16x8, *(const uint4*)&Ah[rr]);
            afl[mt] = __builtin_bit_cast(bf16x8, *(const uint4*)&Al[rr]);
        }
#pragma unroll
        for (int nt = 0; nt < 4; ++nt) {
            const int rr = (wn * 64 + nt * 16 + ln) * 40 + quad * 8;
            bf16x8 bfh = __builtin_bit_cast(bf16x8, *(const uint4*)&Bh[rr]);
            bf16x8 bfl = __builtin_bit_cast(bf16x8, *(const uint4*)&Bl[rr]);
#pragma unroll
            for (int mt = 0; mt < 4; ++mt) {
                acc[mt][nt] = __builtin_amdgcn_mfma_f32_16x16x32_bf16(afh[mt], bfh, acc[mt][nt], 0, 0, 0);
                acc[mt][nt] = __builtin_amdgcn_mfma_f32_16x16x32_bf16(afl[mt], bfh, acc[mt][nt], 0, 0, 0);
                acc[mt][nt] = __builtin_amdgcn_mfma_f32_16x16x32_bf16(afh[mt], bfl, acc[mt][nt], 0, 0, 0);
            }
        }
    }

    float bias4[4];
#pragma unroll
    for (int nt = 0; nt < 4; ++nt) bias4[nt] = bias[n0 + wn * 64 + nt * 16 + ln];

    if (mode == 0) {
#pragma unroll
        for (int mt = 0; mt < 4; ++mt) {
            const int rbase = m0 + wm * 64 + mt * 16 + quad * 4;
#pragma unroll
            for (int reg = 0; reg < 4; ++reg) {
                float* cp = C + (size_t)(rbase + reg) * Nc + n0 + wn * 64 + ln;
#pragma unroll
                for (int nt = 0; nt < 4; ++nt)
                    cp[nt * 16] = acc[mt][nt][reg] + bias4[nt];
            }
        }
    } else {
        const int part = n0 / DXC;
        unsigned short* dst = (part == 0) ? qp : (part == 1) ? kp : vp;
        const int cc = (n0 % DXC) + wn * 64 + ln;
#pragma unroll
        for (int mt = 0; mt < 4; ++mt) {
            const int rbase = row_off + m0 + wm * 64 + mt * 16 + quad * 4;
#pragma unroll
            for (int reg = 0; reg < 4; ++reg) {
                unsigned short* cp = dst + (size_t)(rbase + reg) * DXC + cc;
#pragma unroll
                for (int nt = 0; nt < 4; ++nt)
                    cp[nt * 16] = f2bf(acc[mt][nt][reg] + bias4[nt]);
            }
        }
    }
}

// ---------------- per-head rmsnorm (+ rope for x tokens) on bf16 q/k ----------------
__global__ __launch_bounds__(128) void qknorm_rope_kernel(
    unsigned short* __restrict__ qb, unsigned short* __restrict__ kb,
    const float* __restrict__ qnx, const float* __restrict__ knx,
    const float* __restrict__ qny, const float* __restrict__ kny,
    const float* __restrict__ cosp, const float* __restrict__ sinp)
{
    const int bx = blockIdx.x;
    const int which = bx & 1;
    const int h = (bx >> 1) % NH;
    const int t = bx / (2 * NH);
    unsigned short* p = (which ? kb : qb) + (size_t)t * DXC + h * DH;
    const int d = threadIdx.x;
    const float v = bf2f(p[d]);
    float ss = v * v;
#pragma unroll
    for (int m = 1; m < 64; m <<= 1) ss += __shfl_xor(ss, m, 64);
    __shared__ float red[2];
    if ((d & 63) == 0) red[d >> 6] = ss;
    __syncthreads();
    const float tot = red[0] + red[1];
    const float r = rsqrtf(tot * (1.f / 128.f) + RMS_EPS);
    const float* w = (t < NX) ? (which ? knx : qnx) : (which ? kny : qny);
    const float nv = v * r * w[d];
    float outv = nv;
    if (t < NX) {
        const int pidx = d >> 1;
        const float cs = cosp[((size_t)t * NH + h) * 64 + pidx];
        const float sn = sinp[((size_t)t * NH + h) * 64 + pidx];
        const float partner = __shfl_xor(nv, 1, 64);
        outv = ((d & 1) == 0) ? (nv * cs - partner * sn)
                              : (partner * sn + nv * cs);
    }
    p[d] = f2bf(outv);
}

// ---------------- flash attention, bf16 MFMA 16x16x32 ----------------
// Round-2 restructure: Q fragments direct from global (no Qs LDS -> 44 KB LDS,
// 3 blocks/CU), K/V prefetched into registers one tile ahead (T14 async-stage:
// global latency hides under QK+softmax+PV), s_setprio around MFMA clusters (T5).
#define BQ 64
#define BKV 64
#define NQT ((NTOT + BQ - 1) / BQ)   // 36
#define ATTN_SCALE 0.08838834764831845f

__global__ __launch_bounds__(256, 3) void attn_kernel(
    const unsigned short* __restrict__ qb, const unsigned short* __restrict__ kb,
    const unsigned short* __restrict__ vb,
    unsigned short* __restrict__ out_hi, unsigned short* __restrict__ out_lo,
    const int* __restrict__ idx)
{
    __shared__ unsigned short Ks[64 * 136];
    __shared__ unsigned int   Vt[128 * 36];
    __shared__ unsigned short Ps[4][16 * 72];

    const int h  = blockIdx.x / NQT;
    const int qt = blockIdx.x % NQT;
    const int q0 = qt * BQ;
    const int tid  = threadIdx.x;
    const int wave = tid >> 6;
    const int lane = tid & 63;
    const int quad = lane >> 4;
    const int ln   = lane & 15;
    const int ch   = tid & 15;       // staging col chunk
    const int rb   = tid >> 4;       // staging row base

    // Q fragments direct from global (row-contiguous 16B chunks = MFMA A layout)
    bf16x8 aq[4];
    {
        const int qi = q0 + wave * 16 + ln;
        if (qi < NTOT) {
            const unsigned short* qrow = qb + (size_t)idx[qi] * DXC + h * DH;
#pragma unroll
            for (int c = 0; c < 4; ++c)
                aq[c] = __builtin_bit_cast(bf16x8, *(const uint4*)(qrow + c * 32 + quad * 8));
        } else {
            const uint4 z = make_uint4(0, 0, 0, 0);
#pragma unroll
            for (int c = 0; c < 4; ++c) aq[c] = __builtin_bit_cast(bf16x8, z);
        }
    }

    f32x4 o[8];
#pragma unroll
    for (int dt = 0; dt < 8; ++dt) o[dt] = (f32x4){0.f, 0.f, 0.f, 0.f};
    float m_i[4] = {-1e30f, -1e30f, -1e30f, -1e30f};
    float l_i[4] = {0.f, 0.f, 0.f, 0.f};

    // K/V register prefetch (one tile ahead)
    uint4 kreg[4], vra[2], vrb[2];
    const uint4 z4 = make_uint4(0, 0, 0, 0);
    auto prefetchKV = [&](int kv0) {
#pragma unroll
        for (int it = 0; it < 4; ++it) {
            const int ki = kv0 + rb + it * 16;
            kreg[it] = (ki < NTOT)
                ? *(const uint4*)(kb + (size_t)idx[ki] * DXC + h * DH + ch * 8) : z4;
        }
#pragma unroll
        for (int it = 0; it < 2; ++it) {
            const int pr = rb + it * 16;
            const int k0i = kv0 + pr * 2, k1i = k0i + 1;
            vra[it] = (k0i < NTOT)
                ? *(const uint4*)(vb + (size_t)idx[k0i] * DXC + h * DH + ch * 8) : z4;
            vrb[it] = (k1i < NTOT)
                ? *(const uint4*)(vb + (size_t)idx[k1i] * DXC + h * DH + ch * 8) : z4;
        }
    };
    prefetchKV(0);

    for (int kv0 = 0; kv0 < NTOT; kv0 += BKV) {
        __syncthreads();   // previous tile's LDS reads done
        // write prefetched K tile
#pragma unroll
        for (int it = 0; it < 4; ++it)
            *(uint4*)&Ks[(rb + it * 16) * 136 + ch * 8] = kreg[it];
        // pack + write prefetched V tile (transposed, pair-interleaved)
#pragma unroll
        for (int it = 0; it < 2; ++it) {
            const int pr = rb + it * 16;
            const uint4 a = vra[it], b = vrb[it];
            unsigned int w[8];
            w[0] = (a.x & 0xffffu) | (b.x << 16);  w[1] = (a.x >> 16) | (b.x & 0xffff0000u);
            w[2] = (a.y & 0xffffu) | (b.y << 16);  w[3] = (a.y >> 16) | (b.y & 0xffff0000u);
            w[4] = (a.z & 0xffffu) | (b.z << 16);  w[5] = (a.z >> 16) | (b.z & 0xffff0000u);
            w[6] = (a.w & 0xffffu) | (b.w << 16);  w[7] = (a.w >> 16) | (b.w & 0xffff0000u);
#pragma unroll
            for (int s = 0; s < 8; ++s) {
                const int e = (s + ch) & 7;
                Vt[(ch * 8 + e) * 36 + pr] = w[e];
            }
        }
        __syncthreads();

        // issue next tile's global loads now; latency hides under MFMA+softmax
        if (kv0 + BKV < NTOT) prefetchKV(kv0 + BKV);

        f32x4 sc[4];
        __builtin_amdgcn_s_setprio(1);
#pragma unroll
        for (int t = 0; t < 4; ++t) {
            sc[t] = (f32x4){0.f, 0.f, 0.f, 0.f};
#pragma unroll
            for (int c = 0; c < 4; ++c) {
                bf16x8 bk = __builtin_bit_cast(bf16x8,
                    *(const uint4*)&Ks[(t * 16 + ln) * 136 + c * 32 + quad * 8]);
                sc[t] = __builtin_amdgcn_mfma_f32_16x16x32_bf16(aq[c], bk, sc[t], 0, 0, 0);
            }
        }
        __builtin_amdgcn_s_setprio(0);

        float alpha[4];
#pragma unroll
        for (int r = 0; r < 4; ++r) {
            float mt = -1e30f;
#pragma unroll
            for (int t = 0; t < 4; ++t) {
                float sv = sc[t][r] * ATTN_SCALE;
                if (kv0 + t * 16 + ln >= NTOT) sv = -1e30f;
                sc[t][r] = sv;
                mt = fmaxf(mt, sv);
            }
#pragma unroll
            for (int mm = 1; mm < 16; mm <<= 1) mt = fmaxf(mt, __shfl_xor(mt, mm, 64));
            const float mn = fmaxf(m_i[r], mt);
            alpha[r] = __expf(m_i[r] - mn);
            m_i[r] = mn;
            float rs = 0.f;
#pragma unroll
            for (int t = 0; t < 4; ++t) {
                const float pv = __expf(sc[t][r] - mn);
                sc[t][r] = pv;
                rs += pv;
            }
#pragma unroll
            for (int mm = 1; mm < 16; mm <<= 1) rs += __shfl_xor(rs, mm, 64);
            l_i[r] = l_i[r] * alpha[r] + rs;
        }

        unsigned short* psw = Ps[wave];
#pragma unroll
        for (int t = 0; t < 4; ++t)
#pragma unroll
            for (int r = 0; r < 4; ++r)
                psw[(quad * 4 + r) * 72 + t * 16 + ln] = f2bf(sc[t][r]);

#pragma unroll
        for (int dt = 0; dt < 8; ++dt)
#pragma unroll
            for (int r = 0; r < 4; ++r) o[dt][r] *= alpha[r];

        bf16x8 ap0 = __builtin_bit_cast(bf16x8, *(const uint4*)&psw[ln * 72 + quad * 8]);
        bf16x8 ap1 = __builtin_bit_cast(bf16x8, *(const uint4*)&psw[ln * 72 + 32 + quad * 8]);
        __builtin_amdgcn_s_setprio(1);
#pragma unroll
        for (int dt = 0; dt < 8; ++dt) {
            bf16x8 bv0 = __builtin_bit_cast(bf16x8,
                *(const uint4*)&Vt[(dt * 16 + ln) * 36 + quad * 4]);
            o[dt] = __builtin_amdgcn_mfma_f32_16x16x32_bf16(ap0, bv0, o[dt], 0, 0, 0);
            bf16x8 bv1 = __builtin_bit_cast(bf16x8,
                *(const uint4*)&Vt[(dt * 16 + ln) * 36 + 16 + quad * 4]);
            o[dt] = __builtin_amdgcn_mfma_f32_16x16x32_bf16(ap1, bv1, o[dt], 0, 0, 0);
        }
        __builtin_amdgcn_s_setprio(0);
    }

#pragma unroll
    for (int r = 0; r < 4; ++r) {
        const int qrow = q0 + wave * 16 + quad * 4 + r;
        if (qrow >= NTOT) continue;
        const int tok = idx[qrow];
        const float inv = 1.f / l_i[r];
        unsigned short* hp = out_hi + (size_t)tok * DXC + h * DH + ln;
        unsigned short* lp = out_lo + (size_t)tok * DXC + h * DH + ln;
#pragma unroll
        for (int dt = 0; dt < 8; ++dt) {
            const float v = o[dt][r] * inv;
            const unsigned int u = __float_as_uint(v);
            hp[dt * 16] = (unsigned short)(u >> 16);
            lp[dt * 16] = f2bf(v - __uint_as_float(u & 0xffff0000u));
        }
    }
}

extern "C" void kernel_launch(void* const* d_in, const int* in_sizes, int n_in,
                              void* d_out, int out_size, void* d_ws, size_t ws_size,
                              hipStream_t stream)
{
    const float* x        = (const float*)d_in[0];
    const float* y        = (const float*)d_in[1];
    const float* scale_x  = (const float*)d_in[2];
    const float* scale_y  = (const float*)d_in[3];
    const float* rope_cos = (const float*)d_in[4];
    const float* rope_sin = (const float*)d_in[5];
    const float* W_qkv_x  = (const float*)d_in[6];
    const float* b_qkv_x  = (const float*)d_in[7];
    const float* W_qkv_y  = (const float*)d_in[8];
    const float* b_qkv_y  = (const float*)d_in[9];
    const float* q_norm_x = (const float*)d_in[10];
    const float* k_norm_x = (const float*)d_in[11];
    const float* q_norm_y = (const float*)d_in[12];
    const float* k_norm_y = (const float*)d_in[13];
    const float* W_proj_x = (const float*)d_in[14];
    const float* b_proj_x = (const float*)d_in[15];
    const float* W_proj_y = (const float*)d_in[16];
    const float* b_proj_y = (const float*)d_in[17];
    const int*   vidx     = (const int*)d_in[18];
    float* out = (float*)d_out;

    unsigned short* wsu = (unsigned short*)d_ws;
    const size_t SEG = (size_t)NLTOK * DXC;   // 7,077,888 elements
    unsigned short* q16     = wsu;
    unsigned short* k16     = wsu + SEG;
    unsigned short* v16     = wsu + 2 * SEG;
    unsigned short* attn_hi = wsu + 3 * SEG;
    unsigned short* attn_lo = wsu + 4 * SEG;
    unsigned short* xm_hi   = wsu + 5 * SEG;
    unsigned short* xm_lo   = wsu + 6 * SEG;
    unsigned short* ym_hi   = xm_hi + (size_t)NX * DXC;  // fits in SEG slack
    unsigned short* ym_lo   = xm_lo + (size_t)NX * DXC;

    // 0) zero attention scatter target (hi+lo contiguous)
    hipMemsetAsync(attn_hi, 0, 2 * SEG * sizeof(unsigned short), stream);

    // 1) rmsnorm * (1 + scale), pre-split hi/lo
    rmsnorm_scale_split_kernel<<<NX, 256, 0, stream>>>(x, scale_x, xm_hi, xm_lo, DXC);
    rmsnorm_scale_split_kernel<<<LY, 256, 0, stream>>>(y, scale_y, ym_hi, ym_lo, DYC);

    // 2) QKV GEMMs (split-bf16 3-term), scatter into bf16 q/k/v
    gemm_split_kernel<<<dim3(9216 / 128, NX / 128), 256, 0, stream>>>(
        xm_hi, xm_lo, W_qkv_x, b_qkv_x, nullptr, q16, k16, v16, 0, DXC, 1, 0);
    gemm_split_kernel<<<dim3(9216 / 128, LY / 128), 256, 0, stream>>>(
        ym_hi, ym_lo, W_qkv_y, b_qkv_y, nullptr, q16, k16, v16, 0, DYC, 1, NX);

    // 3) per-head q/k rmsnorm (+rope for x tokens)
    qknorm_rope_kernel<<<NLTOK * NH * 2, 128, 0, stream>>>(
        q16, k16, q_norm_x, k_norm_x, q_norm_y, k_norm_y, rope_cos, rope_sin);

    // 4) flash attention -> split hi/lo output
    attn_kernel<<<NH * NQT, 256, 0, stream>>>(q16, k16, v16, attn_hi, attn_lo, vidx);

    // 5) output projections (split-bf16 3-term)
    gemm_split_kernel<<<dim3(DXC / 128, NX / 128), 256, 0, stream>>>(
        attn_hi, attn_lo, W_proj_x, b_proj_x, out, nullptr, nullptr, nullptr,
        DXC, DXC, 0, 0);
    gemm_split_kernel<<<dim3(DYC / 128, LY / 128), 256, 0, stream>>>(
        attn_hi + (size_t)NX * DXC, attn_lo + (size_t)NX * DXC,
        W_proj_y, b_proj_y, out + (size_t)NX * DXC, nullptr, nullptr, nullptr,
        DYC, DXC, 0, 0);
}

// Round 7
// 1479.765 us; speedup vs baseline: 1.0543x; 1.0543x over previous
//
#include <hip/hip_runtime.h>
#include <math.h>

#define NX 2048
#define LY 256
#define NH 24
#define DH 128
#define DXC 3072
#define DYC 1536
#define NLTOK 2304
#define NTOT 2248
#define KVSPLIT 1124   // NTOT/2
#define OPS 130        // opart row stride: 128 o-values + 1 float (m or l)
#define RMS_EPS 1e-6f

typedef __bf16 bf16x8 __attribute__((ext_vector_type(8)));
typedef float f32x4 __attribute__((ext_vector_type(4)));

static __device__ __forceinline__ unsigned short f2bf(float f) {
    union { float f; unsigned int u; } x; x.f = f;
    unsigned int r = (x.u + 0x7fffu + ((x.u >> 16) & 1u)) >> 16;
    return (unsigned short)r;
}
static __device__ __forceinline__ float bf2f(unsigned short u) {
    union { unsigned int u; float f; } x; x.u = ((unsigned int)u) << 16;
    return x.f;
}
static __device__ __forceinline__ unsigned int pack2(float lo, float hi) {
    return (unsigned int)f2bf(lo) | ((unsigned int)f2bf(hi) << 16);
}
// split fp32 -> hi (truncate) + lo (RN of remainder); residual <= 2^-17 |x|
static __device__ __forceinline__ void split4(float4 f, uint2& h, uint2& l) {
    unsigned int ux = __float_as_uint(f.x), uy = __float_as_uint(f.y);
    unsigned int uz = __float_as_uint(f.z), uw = __float_as_uint(f.w);
    h.x = (ux >> 16) | (uy & 0xffff0000u);
    h.y = (uz >> 16) | (uw & 0xffff0000u);
    float lx = f.x - __uint_as_float(ux & 0xffff0000u);
    float ly = f.y - __uint_as_float(uy & 0xffff0000u);
    float lz = f.z - __uint_as_float(uz & 0xffff0000u);
    float lw = f.w - __uint_as_float(uw & 0xffff0000u);
    l.x = pack2(lx, ly);
    l.y = pack2(lz, lw);
}

// ---------------- rmsnorm * (1 + scale) -> split bf16 hi/lo ----------------
__global__ __launch_bounds__(256) void rmsnorm_scale_split_kernel(
    const float* __restrict__ in, const float* __restrict__ scale,
    unsigned short* __restrict__ out_hi, unsigned short* __restrict__ out_lo,
    int cols)
{
    const int row = blockIdx.x;
    const int tid = threadIdx.x;
    const float* rp = in + (size_t)row * cols;
    const int nv = cols >> 2;
    float4 vals[3];
    float ss = 0.f;
    int cnt = 0;
    for (int c4 = tid; c4 < nv; c4 += 256) {
        float4 v = ((const float4*)rp)[c4];
        vals[cnt++] = v;
        ss += v.x * v.x + v.y * v.y + v.z * v.z + v.w * v.w;
    }
#pragma unroll
    for (int m = 1; m < 64; m <<= 1) ss += __shfl_xor(ss, m, 64);
    __shared__ float red[4];
    if ((tid & 63) == 0) red[tid >> 6] = ss;
    __syncthreads();
    const float tot = red[0] + red[1] + red[2] + red[3];
    const float r = rsqrtf(tot / (float)cols + RMS_EPS);
    unsigned short* oh = out_hi + (size_t)row * cols;
    unsigned short* ol = out_lo + (size_t)row * cols;
    cnt = 0;
    for (int c4 = tid; c4 < nv; c4 += 256) {
        float4 v = vals[cnt++];
        float4 s = ((const float4*)scale)[c4];
        float4 o;
        o.x = v.x * r * (1.f + s.x);
        o.y = v.y * r * (1.f + s.y);
        o.z = v.z * r * (1.f + s.z);
        o.w = v.w * r * (1.f + s.w);
        uint2 h, l;
        split4(o, h, l);
        ((uint2*)oh)[c4] = h;
        ((uint2*)ol)[c4] = l;
    }
}

// ---------------- split-bf16 3-term MFMA GEMM ----------------
__global__ __launch_bounds__(256) void gemm_split_kernel(
    const unsigned short* __restrict__ Ahg, const unsigned short* __restrict__ Alg,
    const float* __restrict__ Bg, const float* __restrict__ bias,
    float* __restrict__ C,
    unsigned short* __restrict__ qp, unsigned short* __restrict__ kp,
    unsigned short* __restrict__ vp,
    int Nc, int K, int mode, int row_off)
{
    __shared__ unsigned short Ah[128 * 40];   // rows stride 40 (80B): b128 reads 2-way
    __shared__ unsigned short Al[128 * 40];
    __shared__ unsigned short Bh[128 * 40];
    __shared__ unsigned short Bl[128 * 40];

    const int tid = threadIdx.x;
    const int n0 = blockIdx.x * 128;
    const int m0 = blockIdx.y * 128;
    const int wave = tid >> 6, lane = tid & 63;
    const int quad = lane >> 4, ln = lane & 15;
    const int wm = wave >> 1, wn = wave & 1;
    const int sr = tid >> 1;            // staged row 0..127
    const int sk = (tid & 1) * 16;      // k-half (elements)

    const unsigned short* Abh = Ahg + (size_t)(m0 + sr) * K + sk;
    const unsigned short* Abl = Alg + (size_t)(m0 + sr) * K + sk;
    const float* Bb = Bg + (size_t)(n0 + sr) * K + sk;

    f32x4 acc[4][4];
#pragma unroll
    for (int i = 0; i < 4; ++i)
#pragma unroll
        for (int j = 0; j < 4; ++j) acc[i][j] = (f32x4){0.f, 0.f, 0.f, 0.f};

    // prefetch k0 = 0, pre-split B into register words
    uint4 pah0 = *(const uint4*)Abh;
    uint4 pah1 = *(const uint4*)(Abh + 8);
    uint4 pal0 = *(const uint4*)Abl;
    uint4 pal1 = *(const uint4*)(Abl + 8);
    uint4 pbh0, pbh1, pbl0, pbl1;
    {
        float4 b0 = ((const float4*)Bb)[0];
        float4 b1 = ((const float4*)Bb)[1];
        float4 b2 = ((const float4*)Bb)[2];
        float4 b3 = ((const float4*)Bb)[3];
        uint2 h0, l0, h1, l1, h2, l2, h3, l3;
        split4(b0, h0, l0); split4(b1, h1, l1);
        split4(b2, h2, l2); split4(b3, h3, l3);
        pbh0 = make_uint4(h0.x, h0.y, h1.x, h1.y);
        pbh1 = make_uint4(h2.x, h2.y, h3.x, h3.y);
        pbl0 = make_uint4(l0.x, l0.y, l1.x, l1.y);
        pbl1 = make_uint4(l2.x, l2.y, l3.x, l3.y);
    }

    for (int k0 = 0; k0 < K; k0 += 32) {
        __syncthreads();   // previous fragment reads done
        *(uint4*)&Ah[sr * 40 + sk]     = pah0;
        *(uint4*)&Ah[sr * 40 + sk + 8] = pah1;
        *(uint4*)&Al[sr * 40 + sk]     = pal0;
        *(uint4*)&Al[sr * 40 + sk + 8] = pal1;
        *(uint4*)&Bh[sr * 40 + sk]     = pbh0;
        *(uint4*)&Bh[sr * 40 + sk + 8] = pbh1;
        *(uint4*)&Bl[sr * 40 + sk]     = pbl0;
        *(uint4*)&Bl[sr * 40 + sk + 8] = pbl1;
        __syncthreads();

        if (k0 + 32 < K) {   // prefetch + split next tile (overlaps MFMA below)
            const unsigned short* ah2 = Abh + k0 + 32;
            const unsigned short* al2 = Abl + k0 + 32;
            const float* b2p = Bb + k0 + 32;
            pah0 = *(const uint4*)ah2;  pah1 = *(const uint4*)(ah2 + 8);
            pal0 = *(const uint4*)al2;  pal1 = *(const uint4*)(al2 + 8);
            float4 b0 = ((const float4*)b2p)[0];
            float4 b1 = ((const float4*)b2p)[1];
            float4 b2 = ((const float4*)b2p)[2];
            float4 b3 = ((const float4*)b2p)[3];
            uint2 h0, l0, h1, l1, h2, l2, h3, l3;
            split4(b0, h0, l0); split4(b1, h1, l1);
            split4(b2, h2, l2); split4(b3, h3, l3);
            pbh0 = make_uint4(h0.x, h0.y, h1.x, h1.y);
            pbh1 = make_uint4(h2.x, h2.y, h3.x, h3.y);
            pbl0 = make_uint4(l0.x, l0.y, l1.x, l1.y);
            pbl1 = make_uint4(l2.x, l2.y, l3.x, l3.y);
        }

        bf16x8 afh[4], afl[4];
#pragma unroll
        for (int mt = 0; mt < 4; ++mt) {
            const int rr = (wm * 64 + mt * 16 + ln) * 40 + quad * 8;
            afh[mt] = __builtin_bit_cast(bf16x8, *(const uint4*)&Ah[rr]);
            afl[mt] = __builtin_bit_cast(bf16x8, *(const uint4*)&Al[rr]);
        }
#pragma unroll
        for (int nt = 0; nt < 4; ++nt) {
            const int rr = (wn * 64 + nt * 16 + ln) * 40 + quad * 8;
            bf16x8 bfh = __builtin_bit_cast(bf16x8, *(const uint4*)&Bh[rr]);
            bf16x8 bfl = __builtin_bit_cast(bf16x8, *(const uint4*)&Bl[rr]);
#pragma unroll
            for (int mt = 0; mt < 4; ++mt) {
                acc[mt][nt] = __builtin_amdgcn_mfma_f32_16x16x32_bf16(afh[mt], bfh, acc[mt][nt], 0, 0, 0);
                acc[mt][nt] = __builtin_amdgcn_mfma_f32_16x16x32_bf16(afl[mt], bfh, acc[mt][nt], 0, 0, 0);
                acc[mt][nt] = __builtin_amdgcn_mfma_f32_16x16x32_bf16(afh[mt], bfl, acc[mt][nt], 0, 0, 0);
            }
        }
    }

    float bias4[4];
#pragma unroll
    for (int nt = 0; nt < 4; ++nt) bias4[nt] = bias[n0 + wn * 64 + nt * 16 + ln];

    if (mode == 0) {
#pragma unroll
        for (int mt = 0; mt < 4; ++mt) {
            const int rbase = m0 + wm * 64 + mt * 16 + quad * 4;
#pragma unroll
            for (int reg = 0; reg < 4; ++reg) {
                float* cp = C + (size_t)(rbase + reg) * Nc + n0 + wn * 64 + ln;
#pragma unroll
                for (int nt = 0; nt < 4; ++nt)
                    cp[nt * 16] = acc[mt][nt][reg] + bias4[nt];
            }
        }
    } else {
        const int part = n0 / DXC;
        unsigned short* dst = (part == 0) ? qp : (part == 1) ? kp : vp;
        const int cc = (n0 % DXC) + wn * 64 + ln;
#pragma unroll
        for (int mt = 0; mt < 4; ++mt) {
            const int rbase = row_off + m0 + wm * 64 + mt * 16 + quad * 4;
#pragma unroll
            for (int reg = 0; reg < 4; ++reg) {
                unsigned short* cp = dst + (size_t)(rbase + reg) * DXC + cc;
#pragma unroll
                for (int nt = 0; nt < 4; ++nt)
                    cp[nt * 16] = f2bf(acc[mt][nt][reg] + bias4[nt]);
            }
        }
    }
}

// ---------------- per-head rmsnorm (+ rope for x tokens) on bf16 q/k ----------------
__global__ __launch_bounds__(128) void qknorm_rope_kernel(
    unsigned short* __restrict__ qb, unsigned short* __restrict__ kb,
    const float* __restrict__ qnx, const float* __restrict__ knx,
    const float* __restrict__ qny, const float* __restrict__ kny,
    const float* __restrict__ cosp, const float* __restrict__ sinp)
{
    const int bx = blockIdx.x;
    const int which = bx & 1;
    const int h = (bx >> 1) % NH;
    const int t = bx / (2 * NH);
    unsigned short* p = (which ? kb : qb) + (size_t)t * DXC + h * DH;
    const int d = threadIdx.x;
    const float v = bf2f(p[d]);
    float ss = v * v;
#pragma unroll
    for (int m = 1; m < 64; m <<= 1) ss += __shfl_xor(ss, m, 64);
    __shared__ float red[2];
    if ((d & 63) == 0) red[d >> 6] = ss;
    __syncthreads();
    const float tot = red[0] + red[1];
    const float r = rsqrtf(tot * (1.f / 128.f) + RMS_EPS);
    const float* w = (t < NX) ? (which ? knx : qnx) : (which ? kny : qny);
    const float nv = v * r * w[d];
    float outv = nv;
    if (t < NX) {
        const int pidx = d >> 1;
        const float cs = cosp[((size_t)t * NH + h) * 64 + pidx];
        const float sn = sinp[((size_t)t * NH + h) * 64 + pidx];
        const float partner = __shfl_xor(nv, 1, 64);
        outv = ((d & 1) == 0) ? (nv * cs - partner * sn)
                              : (partner * sn + nv * cs);
    }
    p[d] = f2bf(outv);
}

// ---------------- flash attention, bf16 MFMA 16x16x32, KV-split x2 ----------------
// 864 -> 1728 blocks via 2-way KV split (blockIdx.y = split). Each block covers
// kv rows [s*1124, min(NTOT,(s+1)*1124)), writes UNNORMALIZED partial o (hi/lo
// bf16, row stride 130) with m (hi buf) / l (lo buf) packed at element 128.
// Partial buffers each span 2 SEG: opart_hi at ws+3*SEG, opart_lo at ws+5*SEG.
#define BQ 64
#define BKV 64
#define NQT ((NTOT + BQ - 1) / BQ)   // 36
#define ATTN_SCALE 0.08838834764831845f

__global__ __launch_bounds__(256, 3) void attn_kernel(
    const unsigned short* __restrict__ qb, const unsigned short* __restrict__ kb,
    const unsigned short* __restrict__ vb,
    unsigned short* __restrict__ ophi, unsigned short* __restrict__ oplo,
    const int* __restrict__ idx)
{
    __shared__ unsigned short Ks[64 * 136];
    __shared__ unsigned int   Vt[128 * 36];
    __shared__ unsigned short Ps[4][16 * 72];

    const int h  = blockIdx.x / NQT;
    const int qt = blockIdx.x % NQT;
    const int s  = blockIdx.y;                 // kv split
    const int kv_beg = s * KVSPLIT;
    const int kv_end = (s == 0) ? KVSPLIT : NTOT;
    const int q0 = qt * BQ;
    const int tid  = threadIdx.x;
    const int wave = tid >> 6;
    const int lane = tid & 63;
    const int quad = lane >> 4;
    const int ln   = lane & 15;
    const int ch   = tid & 15;       // staging col chunk
    const int rb   = tid >> 4;       // staging row base

    // Q fragments direct from global (row-contiguous 16B chunks = MFMA A layout)
    bf16x8 aq[4];
    {
        const int qi = q0 + wave * 16 + ln;
        if (qi < NTOT) {
            const unsigned short* qrow = qb + (size_t)idx[qi] * DXC + h * DH;
#pragma unroll
            for (int c = 0; c < 4; ++c)
                aq[c] = __builtin_bit_cast(bf16x8, *(const uint4*)(qrow + c * 32 + quad * 8));
        } else {
            const uint4 z = make_uint4(0, 0, 0, 0);
#pragma unroll
            for (int c = 0; c < 4; ++c) aq[c] = __builtin_bit_cast(bf16x8, z);
        }
    }

    f32x4 o[8];
#pragma unroll
    for (int dt = 0; dt < 8; ++dt) o[dt] = (f32x4){0.f, 0.f, 0.f, 0.f};
    float m_i[4] = {-1e30f, -1e30f, -1e30f, -1e30f};
    float l_i[4] = {0.f, 0.f, 0.f, 0.f};

    // K/V register prefetch (one tile ahead)
    uint4 kreg[4], vra[2], vrb[2];
    const uint4 z4 = make_uint4(0, 0, 0, 0);
    auto prefetchKV = [&](int kv0) {
#pragma unroll
        for (int it = 0; it < 4; ++it) {
            const int ki = kv0 + rb + it * 16;
            kreg[it] = (ki < kv_end)
                ? *(const uint4*)(kb + (size_t)idx[ki] * DXC + h * DH + ch * 8) : z4;
        }
#pragma unroll
        for (int it = 0; it < 2; ++it) {
            const int pr = rb + it * 16;
            const int k0i = kv0 + pr * 2, k1i = k0i + 1;
            vra[it] = (k0i < kv_end)
                ? *(const uint4*)(vb + (size_t)idx[k0i] * DXC + h * DH + ch * 8) : z4;
            vrb[it] = (k1i < kv_end)
                ? *(const uint4*)(vb + (size_t)idx[k1i] * DXC + h * DH + ch * 8) : z4;
        }
    };
    prefetchKV(kv_beg);

    for (int kv0 = kv_beg; kv0 < kv_end; kv0 += BKV) {
        __syncthreads();   // previous tile's LDS reads done
        // write prefetched K tile
#pragma unroll
        for (int it = 0; it < 4; ++it)
            *(uint4*)&Ks[(rb + it * 16) * 136 + ch * 8] = kreg[it];
        // pack + write prefetched V tile (transposed, pair-interleaved)
#pragma unroll
        for (int it = 0; it < 2; ++it) {
            const int pr = rb + it * 16;
            const uint4 a = vra[it], b = vrb[it];
            unsigned int w[8];
            w[0] = (a.x & 0xffffu) | (b.x << 16);  w[1] = (a.x >> 16) | (b.x & 0xffff0000u);
            w[2] = (a.y & 0xffffu) | (b.y << 16);  w[3] = (a.y >> 16) | (b.y & 0xffff0000u);
            w[4] = (a.z & 0xffffu) | (b.z << 16);  w[5] = (a.z >> 16) | (b.z & 0xffff0000u);
            w[6] = (a.w & 0xffffu) | (b.w << 16);  w[7] = (a.w >> 16) | (b.w & 0xffff0000u);
#pragma unroll
            for (int ss2 = 0; ss2 < 8; ++ss2) {
                const int e = (ss2 + ch) & 7;
                Vt[(ch * 8 + e) * 36 + pr] = w[e];
            }
        }
        __syncthreads();

        // issue next tile's global loads now; latency hides under MFMA+softmax
        if (kv0 + BKV < kv_end) prefetchKV(kv0 + BKV);

        f32x4 sc[4];
        __builtin_amdgcn_s_setprio(1);
#pragma unroll
        for (int t = 0; t < 4; ++t) {
            sc[t] = (f32x4){0.f, 0.f, 0.f, 0.f};
#pragma unroll
            for (int c = 0; c < 4; ++c) {
                bf16x8 bk = __builtin_bit_cast(bf16x8,
                    *(const uint4*)&Ks[(t * 16 + ln) * 136 + c * 32 + quad * 8]);
                sc[t] = __builtin_amdgcn_mfma_f32_16x16x32_bf16(aq[c], bk, sc[t], 0, 0, 0);
            }
        }
        __builtin_amdgcn_s_setprio(0);

        float alpha[4];
#pragma unroll
        for (int r = 0; r < 4; ++r) {
            float mt = -1e30f;
#pragma unroll
            for (int t = 0; t < 4; ++t) {
                float sv = sc[t][r] * ATTN_SCALE;
                if (kv0 + t * 16 + ln >= kv_end) sv = -1e30f;
                sc[t][r] = sv;
                mt = fmaxf(mt, sv);
            }
#pragma unroll
            for (int mm = 1; mm < 16; mm <<= 1) mt = fmaxf(mt, __shfl_xor(mt, mm, 64));
            const float mn = fmaxf(m_i[r], mt);
            alpha[r] = __expf(m_i[r] - mn);
            m_i[r] = mn;
            float rs = 0.f;
#pragma unroll
            for (int t = 0; t < 4; ++t) {
                const float pv = __expf(sc[t][r] - mn);
                sc[t][r] = pv;
                rs += pv;
            }
#pragma unroll
            for (int mm = 1; mm < 16; mm <<= 1) rs += __shfl_xor(rs, mm, 64);
            l_i[r] = l_i[r] * alpha[r] + rs;
        }

        unsigned short* psw = Ps[wave];
#pragma unroll
        for (int t = 0; t < 4; ++t)
#pragma unroll
            for (int r = 0; r < 4; ++r)
                psw[(quad * 4 + r) * 72 + t * 16 + ln] = f2bf(sc[t][r]);

#pragma unroll
        for (int dt = 0; dt < 8; ++dt)
#pragma unroll
            for (int r = 0; r < 4; ++r) o[dt][r] *= alpha[r];

        bf16x8 ap0 = __builtin_bit_cast(bf16x8, *(const uint4*)&psw[ln * 72 + quad * 8]);
        bf16x8 ap1 = __builtin_bit_cast(bf16x8, *(const uint4*)&psw[ln * 72 + 32 + quad * 8]);
        __builtin_amdgcn_s_setprio(1);
#pragma unroll
        for (int dt = 0; dt < 8; ++dt) {
            bf16x8 bv0 = __builtin_bit_cast(bf16x8,
                *(const uint4*)&Vt[(dt * 16 + ln) * 36 + quad * 4]);
            o[dt] = __builtin_amdgcn_mfma_f32_16x16x32_bf16(ap0, bv0, o[dt], 0, 0, 0);
            bf16x8 bv1 = __builtin_bit_cast(bf16x8,
                *(const uint4*)&Vt[(dt * 16 + ln) * 36 + 16 + quad * 4]);
            o[dt] = __builtin_amdgcn_mfma_f32_16x16x32_bf16(ap1, bv1, o[dt], 0, 0, 0);
        }
        __builtin_amdgcn_s_setprio(0);
    }

    // partial epilogue: UNNORMALIZED o (hi/lo, stride OPS) + m/l at element 128
    const size_t obase = (size_t)(s * NH + h) * NTOT;
#pragma unroll
    for (int r = 0; r < 4; ++r) {
        const int qrow = q0 + wave * 16 + quad * 4 + r;
        if (qrow >= NTOT) continue;
        const size_t row = obase + qrow;
        unsigned short* hp = ophi + row * OPS + ln;
        unsigned short* lp = oplo + row * OPS + ln;
#pragma unroll
        for (int dt = 0; dt < 8; ++dt) {
            const float v = o[dt][r];
            const unsigned int u = __float_as_uint(v);
            hp[dt * 16] = (unsigned short)(u >> 16);
            lp[dt * 16] = f2bf(v - __uint_as_float(u & 0xffff0000u));
        }
        if (ln == 0) {
            *(float*)(ophi + row * OPS + DH) = m_i[r];
            *(float*)(oplo + row * OPS + DH) = l_i[r];
        }
    }
}

// ---------------- combine the 2 kv-split partials, scatter by idx ----------------
__global__ __launch_bounds__(256) void attn_combine_kernel(
    const unsigned short* __restrict__ ophi, const unsigned short* __restrict__ oplo,
    unsigned short* __restrict__ out_hi, unsigned short* __restrict__ out_lo,
    const int* __restrict__ idx)
{
    const int wave = threadIdx.x >> 6, lane = threadIdx.x & 63;
    const int qrow = blockIdx.x * 4 + wave;      // grid.x = NTOT/4 = 562, exact
    const int h = blockIdx.y;
    const size_t r0 = (size_t)h * NTOT + qrow;           // split 0 row
    const size_t r1 = (size_t)(NH + h) * NTOT + qrow;    // split 1 row
    const float m0 = *(const float*)(ophi + r0 * OPS + DH);
    const float l0 = *(const float*)(oplo + r0 * OPS + DH);
    const float m1 = *(const float*)(ophi + r1 * OPS + DH);
    const float l1 = *(const float*)(oplo + r1 * OPS + DH);
    const float m  = fmaxf(m0, m1);
    const float w0 = __expf(m0 - m), w1 = __expf(m1 - m);
    const float inv = 1.f / (l0 * w0 + l1 * w1);

    const ushort2 a0 = *(const ushort2*)(ophi + r0 * OPS + 2 * lane);
    const ushort2 b0 = *(const ushort2*)(oplo + r0 * OPS + 2 * lane);
    const ushort2 a1 = *(const ushort2*)(ophi + r1 * OPS + 2 * lane);
    const ushort2 b1 = *(const ushort2*)(oplo + r1 * OPS + 2 * lane);

    float vx = ((bf2f(a0.x) + bf2f(b0.x)) * w0 + (bf2f(a1.x) + bf2f(b1.x)) * w1) * inv;
    float vy = ((bf2f(a0.y) + bf2f(b0.y)) * w0 + (bf2f(a1.y) + bf2f(b1.y)) * w1) * inv;

    ushort2 oh, ol;
    const unsigned int ux = __float_as_uint(vx);
    oh.x = (unsigned short)(ux >> 16);
    ol.x = f2bf(vx - __uint_as_float(ux & 0xffff0000u));
    const unsigned int uy = __float_as_uint(vy);
    oh.y = (unsigned short)(uy >> 16);
    ol.y = f2bf(vy - __uint_as_float(uy & 0xffff0000u));

    const size_t doff = (size_t)idx[qrow] * DXC + h * DH + 2 * lane;
    *(ushort2*)(out_hi + doff) = oh;
    *(ushort2*)(out_lo + doff) = ol;
}

extern "C" void kernel_launch(void* const* d_in, const int* in_sizes, int n_in,
                              void* d_out, int out_size, void* d_ws, size_t ws_size,
                              hipStream_t stream)
{
    const float* x        = (const float*)d_in[0];
    const float* y        = (const float*)d_in[1];
    const float* scale_x  = (const float*)d_in[2];
    const float* scale_y  = (const float*)d_in[3];
    const float* rope_cos = (const float*)d_in[4];
    const float* rope_sin = (const float*)d_in[5];
    const float* W_qkv_x  = (const float*)d_in[6];
    const float* b_qkv_x  = (const float*)d_in[7];
    const float* W_qkv_y  = (const float*)d_in[8];
    const float* b_qkv_y  = (const float*)d_in[9];
    const float* q_norm_x = (const float*)d_in[10];
    const float* k_norm_x = (const float*)d_in[11];
    const float* q_norm_y = (const float*)d_in[12];
    const float* k_norm_y = (const float*)d_in[13];
    const float* W_proj_x = (const float*)d_in[14];
    const float* b_proj_x = (const float*)d_in[15];
    const float* W_proj_y = (const float*)d_in[16];
    const float* b_proj_y = (const float*)d_in[17];
    const int*   vidx     = (const int*)d_in[18];
    float* out = (float*)d_out;

    unsigned short* wsu = (unsigned short*)d_ws;
    const size_t SEG = (size_t)NLTOK * DXC;   // 7,077,888 elements
    unsigned short* q16     = wsu;
    unsigned short* k16     = wsu + SEG;
    unsigned short* v16     = wsu + 2 * SEG;
    unsigned short* xm_hi   = wsu + 5 * SEG;
    unsigned short* xm_lo   = wsu + 6 * SEG;
    unsigned short* ym_hi   = xm_hi + (size_t)NX * DXC;  // fits in SEG slack
    unsigned short* ym_lo   = xm_lo + (size_t)NX * DXC;
    // attn partials: each buffer = 2*NH*NTOT rows * stride 130 = 14,027,520
    // ushorts (~2 SEG). opart_hi spans segs 3-4 (old attn_hi/lo, dead until
    // combine); opart_lo spans segs 5-6 (xm/ym, dead after QKV GEMMs).
    // 3*SEG+14,027,520 = 35,261,184 < 5*SEG; 5*SEG+14,027,520 < 7*SEG. In-bounds.
    unsigned short* opart_hi = wsu + 3 * SEG;
    unsigned short* opart_lo = wsu + 5 * SEG;
    // final attn output (combine target, proj-GEMM A): q16/k16, dead after attn.
    unsigned short* fin_hi = q16;
    unsigned short* fin_lo = k16;

    // 1) rmsnorm * (1 + scale), pre-split hi/lo
    rmsnorm_scale_split_kernel<<<NX, 256, 0, stream>>>(x, scale_x, xm_hi, xm_lo, DXC);
    rmsnorm_scale_split_kernel<<<LY, 256, 0, stream>>>(y, scale_y, ym_hi, ym_lo, DYC);

    // 2) QKV GEMMs (split-bf16 3-term), scatter into bf16 q/k/v
    gemm_split_kernel<<<dim3(9216 / 128, NX / 128), 256, 0, stream>>>(
        xm_hi, xm_lo, W_qkv_x, b_qkv_x, nullptr, q16, k16, v16, 0, DXC, 1, 0);
    gemm_split_kernel<<<dim3(9216 / 128, LY / 128), 256, 0, stream>>>(
        ym_hi, ym_lo, W_qkv_y, b_qkv_y, nullptr, q16, k16, v16, 0, DYC, 1, NX);

    // 3) per-head q/k rmsnorm (+rope for x tokens)
    qknorm_rope_kernel<<<NLTOK * NH * 2, 128, 0, stream>>>(
        q16, k16, q_norm_x, k_norm_x, q_norm_y, k_norm_y, rope_cos, rope_sin);

    // 4) flash attention, 2-way KV split -> partials
    attn_kernel<<<dim3(NH * NQT, 2), 256, 0, stream>>>(
        q16, k16, v16, opart_hi, opart_lo, vidx);

    // 4b) zero the combine scatter target (q16+k16 contiguous; q/k dead now),
    //     then combine partials -> fin (rows not in idx stay zero for proj)
    hipMemsetAsync(fin_hi, 0, 2 * SEG * sizeof(unsigned short), stream);
    attn_combine_kernel<<<dim3(NTOT / 4, NH), 256, 0, stream>>>(
        opart_hi, opart_lo, fin_hi, fin_lo, vidx);

    // 5) output projections (split-bf16 3-term)
    gemm_split_kernel<<<dim3(DXC / 128, NX / 128), 256, 0, stream>>>(
        fin_hi, fin_lo, W_proj_x, b_proj_x, out, nullptr, nullptr, nullptr,
        DXC, DXC, 0, 0);
    gemm_split_kernel<<<dim3(DYC / 128, LY / 128), 256, 0, stream>>>(
        fin_hi + (size_t)NX * DXC, fin_lo + (size_t)NX * DXC,
        W_proj_y, b_proj_y, out + (size_t)NX * DXC, nullptr, nullptr, nullptr,
        DYC, DXC, 0, 0);
}

// Round 8
// 1270.197 us; speedup vs baseline: 1.2283x; 1.1650x over previous
//
#include <hip/hip_runtime.h>
#include <math.h>

#define NX 2048
#define LY 256
#define NH 24
#define DH 128
#define DXC 3072
#define DYC 1536
#define NLTOK 2304
#define NTOT 2248
#define KVSPLIT 1124   // NTOT/2
#define OPS 130        // opart row stride: 128 o-values + 1 float (m or l)
#define RMS_EPS 1e-6f

typedef __bf16 bf16x8 __attribute__((ext_vector_type(8)));
typedef float f32x4 __attribute__((ext_vector_type(4)));

static __device__ __forceinline__ unsigned short f2bf(float f) {
    union { float f; unsigned int u; } x; x.f = f;
    unsigned int r = (x.u + 0x7fffu + ((x.u >> 16) & 1u)) >> 16;
    return (unsigned short)r;
}
static __device__ __forceinline__ float bf2f(unsigned short u) {
    union { unsigned int u; float f; } x; x.u = ((unsigned int)u) << 16;
    return x.f;
}
static __device__ __forceinline__ unsigned int pack2(float lo, float hi) {
    return (unsigned int)f2bf(lo) | ((unsigned int)f2bf(hi) << 16);
}
// split fp32 -> hi (truncate) + lo (RN of remainder); residual <= 2^-17 |x|
static __device__ __forceinline__ void split4(float4 f, uint2& h, uint2& l) {
    unsigned int ux = __float_as_uint(f.x), uy = __float_as_uint(f.y);
    unsigned int uz = __float_as_uint(f.z), uw = __float_as_uint(f.w);
    h.x = (ux >> 16) | (uy & 0xffff0000u);
    h.y = (uz >> 16) | (uw & 0xffff0000u);
    float lx = f.x - __uint_as_float(ux & 0xffff0000u);
    float ly = f.y - __uint_as_float(uy & 0xffff0000u);
    float lz = f.z - __uint_as_float(uz & 0xffff0000u);
    float lw = f.w - __uint_as_float(uw & 0xffff0000u);
    l.x = pack2(lx, ly);
    l.y = pack2(lz, lw);
}

// ---------------- rmsnorm * (1 + scale) -> split bf16 hi/lo ----------------
__global__ __launch_bounds__(256) void rmsnorm_scale_split_kernel(
    const float* __restrict__ in, const float* __restrict__ scale,
    unsigned short* __restrict__ out_hi, unsigned short* __restrict__ out_lo,
    int cols)
{
    const int row = blockIdx.x;
    const int tid = threadIdx.x;
    const float* rp = in + (size_t)row * cols;
    const int nv = cols >> 2;
    float4 vals[3];
    float ss = 0.f;
    int cnt = 0;
    for (int c4 = tid; c4 < nv; c4 += 256) {
        float4 v = ((const float4*)rp)[c4];
        vals[cnt++] = v;
        ss += v.x * v.x + v.y * v.y + v.z * v.z + v.w * v.w;
    }
#pragma unroll
    for (int m = 1; m < 64; m <<= 1) ss += __shfl_xor(ss, m, 64);
    __shared__ float red[4];
    if ((tid & 63) == 0) red[tid >> 6] = ss;
    __syncthreads();
    const float tot = red[0] + red[1] + red[2] + red[3];
    const float r = rsqrtf(tot / (float)cols + RMS_EPS);
    unsigned short* oh = out_hi + (size_t)row * cols;
    unsigned short* ol = out_lo + (size_t)row * cols;
    cnt = 0;
    for (int c4 = tid; c4 < nv; c4 += 256) {
        float4 v = vals[cnt++];
        float4 s = ((const float4*)scale)[c4];
        float4 o;
        o.x = v.x * r * (1.f + s.x);
        o.y = v.y * r * (1.f + s.y);
        o.z = v.z * r * (1.f + s.z);
        o.w = v.w * r * (1.f + s.w);
        uint2 h, l;
        split4(o, h, l);
        ((uint2*)oh)[c4] = h;
        ((uint2*)ol)[c4] = l;
    }
}

// ---------------- split-bf16 3-term MFMA GEMM body ----------------
// C[m,n] = sum_k A[m,k]*B[n,k] + bias[n]; A pre-split (hi/lo bf16), B fp32
// split in-kernel. mode 0: fp32 C (ld=Nc). mode 1: bf16 scatter to q/k/v.
static __device__ __forceinline__ void gemm_split_body(
    const unsigned short* __restrict__ Ahg, const unsigned short* __restrict__ Alg,
    const float* __restrict__ Bg, const float* __restrict__ bias,
    float* __restrict__ C,
    unsigned short* __restrict__ qp, unsigned short* __restrict__ kp,
    unsigned short* __restrict__ vp,
    int Nc, int K, int mode, int row_off, int bx, int by,
    unsigned short* Ah, unsigned short* Al,
    unsigned short* Bh, unsigned short* Bl)
{
    const int tid = threadIdx.x;
    const int n0 = bx * 128;
    const int m0 = by * 128;
    const int wave = tid >> 6, lane = tid & 63;
    const int quad = lane >> 4, ln = lane & 15;
    const int wm = wave >> 1, wn = wave & 1;
    const int sr = tid >> 1;            // staged row 0..127
    const int sk = (tid & 1) * 16;      // k-half (elements)

    const unsigned short* Abh = Ahg + (size_t)(m0 + sr) * K + sk;
    const unsigned short* Abl = Alg + (size_t)(m0 + sr) * K + sk;
    const float* Bb = Bg + (size_t)(n0 + sr) * K + sk;

    f32x4 acc[4][4];
#pragma unroll
    for (int i = 0; i < 4; ++i)
#pragma unroll
        for (int j = 0; j < 4; ++j) acc[i][j] = (f32x4){0.f, 0.f, 0.f, 0.f};

    // prefetch k0 = 0, pre-split B into register words
    uint4 pah0 = *(const uint4*)Abh;
    uint4 pah1 = *(const uint4*)(Abh + 8);
    uint4 pal0 = *(const uint4*)Abl;
    uint4 pal1 = *(const uint4*)(Abl + 8);
    uint4 pbh0, pbh1, pbl0, pbl1;
    {
        float4 b0 = ((const float4*)Bb)[0];
        float4 b1 = ((const float4*)Bb)[1];
        float4 b2 = ((const float4*)Bb)[2];
        float4 b3 = ((const float4*)Bb)[3];
        uint2 h0, l0, h1, l1, h2, l2, h3, l3;
        split4(b0, h0, l0); split4(b1, h1, l1);
        split4(b2, h2, l2); split4(b3, h3, l3);
        pbh0 = make_uint4(h0.x, h0.y, h1.x, h1.y);
        pbh1 = make_uint4(h2.x, h2.y, h3.x, h3.y);
        pbl0 = make_uint4(l0.x, l0.y, l1.x, l1.y);
        pbl1 = make_uint4(l2.x, l2.y, l3.x, l3.y);
    }

    for (int k0 = 0; k0 < K; k0 += 32) {
        __syncthreads();   // previous fragment reads done
        *(uint4*)&Ah[sr * 40 + sk]     = pah0;
        *(uint4*)&Ah[sr * 40 + sk + 8] = pah1;
        *(uint4*)&Al[sr * 40 + sk]     = pal0;
        *(uint4*)&Al[sr * 40 + sk + 8] = pal1;
        *(uint4*)&Bh[sr * 40 + sk]     = pbh0;
        *(uint4*)&Bh[sr * 40 + sk + 8] = pbh1;
        *(uint4*)&Bl[sr * 40 + sk]     = pbl0;
        *(uint4*)&Bl[sr * 40 + sk + 8] = pbl1;
        __syncthreads();

        if (k0 + 32 < K) {   // prefetch + split next tile (overlaps MFMA below)
            const unsigned short* ah2 = Abh + k0 + 32;
            const unsigned short* al2 = Abl + k0 + 32;
            const float* b2p = Bb + k0 + 32;
            pah0 = *(const uint4*)ah2;  pah1 = *(const uint4*)(ah2 + 8);
            pal0 = *(const uint4*)al2;  pal1 = *(const uint4*)(al2 + 8);
            float4 b0 = ((const float4*)b2p)[0];
            float4 b1 = ((const float4*)b2p)[1];
            float4 b2 = ((const float4*)b2p)[2];
            float4 b3 = ((const float4*)b2p)[3];
            uint2 h0, l0, h1, l1, h2, l2, h3, l3;
            split4(b0, h0, l0); split4(b1, h1, l1);
            split4(b2, h2, l2); split4(b3, h3, l3);
            pbh0 = make_uint4(h0.x, h0.y, h1.x, h1.y);
            pbh1 = make_uint4(h2.x, h2.y, h3.x, h3.y);
            pbl0 = make_uint4(l0.x, l0.y, l1.x, l1.y);
            pbl1 = make_uint4(l2.x, l2.y, l3.x, l3.y);
        }

        bf16x8 afh[4], afl[4];
#pragma unroll
        for (int mt = 0; mt < 4; ++mt) {
            const int rr = (wm * 64 + mt * 16 + ln) * 40 + quad * 8;
            afh[mt] = __builtin_bit_cast(bf16x8, *(const uint4*)&Ah[rr]);
            afl[mt] = __builtin_bit_cast(bf16x8, *(const uint4*)&Al[rr]);
        }
#pragma unroll
        for (int nt = 0; nt < 4; ++nt) {
            const int rr = (wn * 64 + nt * 16 + ln) * 40 + quad * 8;
            bf16x8 bfh = __builtin_bit_cast(bf16x8, *(const uint4*)&Bh[rr]);
            bf16x8 bfl = __builtin_bit_cast(bf16x8, *(const uint4*)&Bl[rr]);
#pragma unroll
            for (int mt = 0; mt < 4; ++mt) {
                acc[mt][nt] = __builtin_amdgcn_mfma_f32_16x16x32_bf16(afh[mt], bfh, acc[mt][nt], 0, 0, 0);
                acc[mt][nt] = __builtin_amdgcn_mfma_f32_16x16x32_bf16(afl[mt], bfh, acc[mt][nt], 0, 0, 0);
                acc[mt][nt] = __builtin_amdgcn_mfma_f32_16x16x32_bf16(afh[mt], bfl, acc[mt][nt], 0, 0, 0);
            }
        }
    }

    float bias4[4];
#pragma unroll
    for (int nt = 0; nt < 4; ++nt) bias4[nt] = bias[n0 + wn * 64 + nt * 16 + ln];

    if (mode == 0) {
#pragma unroll
        for (int mt = 0; mt < 4; ++mt) {
            const int rbase = m0 + wm * 64 + mt * 16 + quad * 4;
#pragma unroll
            for (int reg = 0; reg < 4; ++reg) {
                float* cp = C + (size_t)(rbase + reg) * Nc + n0 + wn * 64 + ln;
#pragma unroll
                for (int nt = 0; nt < 4; ++nt)
                    cp[nt * 16] = acc[mt][nt][reg] + bias4[nt];
            }
        }
    } else {
        const int part = n0 / DXC;
        unsigned short* dst = (part == 0) ? qp : (part == 1) ? kp : vp;
        const int cc = (n0 % DXC) + wn * 64 + ln;
#pragma unroll
        for (int mt = 0; mt < 4; ++mt) {
            const int rbase = row_off + m0 + wm * 64 + mt * 16 + quad * 4;
#pragma unroll
            for (int reg = 0; reg < 4; ++reg) {
                unsigned short* cp = dst + (size_t)(rbase + reg) * DXC + cc;
#pragma unroll
                for (int nt = 0; nt < 4; ++nt)
                    cp[nt * 16] = f2bf(acc[mt][nt][reg] + bias4[nt]);
            }
        }
    }
}

// Fused dual-problem GEMM: blockIdx.y < ySplit -> problem 1 (row by);
// else -> problem 2 (row by - ySplit), with nbx2 valid n-blocks (early exit
// before any barrier for the idle tail). Overlaps the small y-GEMM with the
// large x-GEMM in one dispatch (single stream, no serial drain).
__global__ __launch_bounds__(256) void gemm_split_dual_kernel(
    const unsigned short* __restrict__ Ah1, const unsigned short* __restrict__ Al1,
    const float* __restrict__ B1, const float* __restrict__ bias1,
    float* __restrict__ C1,
    unsigned short* __restrict__ qp, unsigned short* __restrict__ kp,
    unsigned short* __restrict__ vp,
    int Nc1, int K1, int mode1, int ro1,
    const unsigned short* __restrict__ Ah2, const unsigned short* __restrict__ Al2,
    const float* __restrict__ B2, const float* __restrict__ bias2,
    float* __restrict__ C2,
    int Nc2, int K2, int mode2, int ro2,
    int ySplit, int nbx2)
{
    __shared__ unsigned short Ah[128 * 40];   // rows stride 40 (80B)
    __shared__ unsigned short Al[128 * 40];
    __shared__ unsigned short Bh[128 * 40];
    __shared__ unsigned short Bl[128 * 40];

    const int bx = blockIdx.x, by = blockIdx.y;
    if (by < ySplit) {
        gemm_split_body(Ah1, Al1, B1, bias1, C1, qp, kp, vp,
                        Nc1, K1, mode1, ro1, bx, by, Ah, Al, Bh, Bl);
    } else {
        if (bx >= nbx2) return;   // uniform, before any barrier
        gemm_split_body(Ah2, Al2, B2, bias2, C2, qp, kp, vp,
                        Nc2, K2, mode2, ro2, bx, by - ySplit, Ah, Al, Bh, Bl);
    }
}

// ---------------- per-head rmsnorm (+ rope for x tokens) on bf16 q/k ----------------
__global__ __launch_bounds__(128) void qknorm_rope_kernel(
    unsigned short* __restrict__ qb, unsigned short* __restrict__ kb,
    const float* __restrict__ qnx, const float* __restrict__ knx,
    const float* __restrict__ qny, const float* __restrict__ kny,
    const float* __restrict__ cosp, const float* __restrict__ sinp)
{
    const int bx = blockIdx.x;
    const int which = bx & 1;
    const int h = (bx >> 1) % NH;
    const int t = bx / (2 * NH);
    unsigned short* p = (which ? kb : qb) + (size_t)t * DXC + h * DH;
    const int d = threadIdx.x;
    const float v = bf2f(p[d]);
    float ss = v * v;
#pragma unroll
    for (int m = 1; m < 64; m <<= 1) ss += __shfl_xor(ss, m, 64);
    __shared__ float red[2];
    if ((d & 63) == 0) red[d >> 6] = ss;
    __syncthreads();
    const float tot = red[0] + red[1];
    const float r = rsqrtf(tot * (1.f / 128.f) + RMS_EPS);
    const float* w = (t < NX) ? (which ? knx : qnx) : (which ? kny : qny);
    const float nv = v * r * w[d];
    float outv = nv;
    if (t < NX) {
        const int pidx = d >> 1;
        const float cs = cosp[((size_t)t * NH + h) * 64 + pidx];
        const float sn = sinp[((size_t)t * NH + h) * 64 + pidx];
        const float partner = __shfl_xor(nv, 1, 64);
        outv = ((d & 1) == 0) ? (nv * cs - partner * sn)
                              : (partner * sn + nv * cs);
    }
    p[d] = f2bf(outv);
}

// ---------------- flash attention, bf16 MFMA 16x16x32, KV-split x2 ----------------
#define BQ 64
#define BKV 64
#define NQT ((NTOT + BQ - 1) / BQ)   // 36
#define ATTN_SCALE 0.08838834764831845f

__global__ __launch_bounds__(256, 3) void attn_kernel(
    const unsigned short* __restrict__ qb, const unsigned short* __restrict__ kb,
    const unsigned short* __restrict__ vb,
    unsigned short* __restrict__ ophi, unsigned short* __restrict__ oplo,
    const int* __restrict__ idx)
{
    __shared__ unsigned short Ks[64 * 136];
    __shared__ unsigned int   Vt[128 * 36];
    __shared__ unsigned short Ps[4][16 * 72];

    const int h  = blockIdx.x / NQT;
    const int qt = blockIdx.x % NQT;
    const int s  = blockIdx.y;                 // kv split
    const int kv_beg = s * KVSPLIT;
    const int kv_end = (s == 0) ? KVSPLIT : NTOT;
    const int q0 = qt * BQ;
    const int tid  = threadIdx.x;
    const int wave = tid >> 6;
    const int lane = tid & 63;
    const int quad = lane >> 4;
    const int ln   = lane & 15;
    const int ch   = tid & 15;       // staging col chunk
    const int rb   = tid >> 4;       // staging row base

    // Q fragments direct from global (row-contiguous 16B chunks = MFMA A layout)
    bf16x8 aq[4];
    {
        const int qi = q0 + wave * 16 + ln;
        if (qi < NTOT) {
            const unsigned short* qrow = qb + (size_t)idx[qi] * DXC + h * DH;
#pragma unroll
            for (int c = 0; c < 4; ++c)
                aq[c] = __builtin_bit_cast(bf16x8, *(const uint4*)(qrow + c * 32 + quad * 8));
        } else {
            const uint4 z = make_uint4(0, 0, 0, 0);
#pragma unroll
            for (int c = 0; c < 4; ++c) aq[c] = __builtin_bit_cast(bf16x8, z);
        }
    }

    f32x4 o[8];
#pragma unroll
    for (int dt = 0; dt < 8; ++dt) o[dt] = (f32x4){0.f, 0.f, 0.f, 0.f};
    float m_i[4] = {-1e30f, -1e30f, -1e30f, -1e30f};
    float l_i[4] = {0.f, 0.f, 0.f, 0.f};

    // K/V register prefetch (one tile ahead)
    uint4 kreg[4], vra[2], vrb[2];
    const uint4 z4 = make_uint4(0, 0, 0, 0);
    auto prefetchKV = [&](int kv0) {
#pragma unroll
        for (int it = 0; it < 4; ++it) {
            const int ki = kv0 + rb + it * 16;
            kreg[it] = (ki < kv_end)
                ? *(const uint4*)(kb + (size_t)idx[ki] * DXC + h * DH + ch * 8) : z4;
        }
#pragma unroll
        for (int it = 0; it < 2; ++it) {
            const int pr = rb + it * 16;
            const int k0i = kv0 + pr * 2, k1i = k0i + 1;
            vra[it] = (k0i < kv_end)
                ? *(const uint4*)(vb + (size_t)idx[k0i] * DXC + h * DH + ch * 8) : z4;
            vrb[it] = (k1i < kv_end)
                ? *(const uint4*)(vb + (size_t)idx[k1i] * DXC + h * DH + ch * 8) : z4;
        }
    };
    prefetchKV(kv_beg);

    for (int kv0 = kv_beg; kv0 < kv_end; kv0 += BKV) {
        __syncthreads();   // previous tile's LDS reads done
        // write prefetched K tile
#pragma unroll
        for (int it = 0; it < 4; ++it)
            *(uint4*)&Ks[(rb + it * 16) * 136 + ch * 8] = kreg[it];
        // pack + write prefetched V tile (transposed, pair-interleaved)
#pragma unroll
        for (int it = 0; it < 2; ++it) {
            const int pr = rb + it * 16;
            const uint4 a = vra[it], b = vrb[it];
            unsigned int w[8];
            w[0] = (a.x & 0xffffu) | (b.x << 16);  w[1] = (a.x >> 16) | (b.x & 0xffff0000u);
            w[2] = (a.y & 0xffffu) | (b.y << 16);  w[3] = (a.y >> 16) | (b.y & 0xffff0000u);
            w[4] = (a.z & 0xffffu) | (b.z << 16);  w[5] = (a.z >> 16) | (b.z & 0xffff0000u);
            w[6] = (a.w & 0xffffu) | (b.w << 16);  w[7] = (a.w >> 16) | (b.w & 0xffff0000u);
#pragma unroll
            for (int ss2 = 0; ss2 < 8; ++ss2) {
                const int e = (ss2 + ch) & 7;
                Vt[(ch * 8 + e) * 36 + pr] = w[e];
            }
        }
        __syncthreads();

        // issue next tile's global loads now; latency hides under MFMA+softmax
        if (kv0 + BKV < kv_end) prefetchKV(kv0 + BKV);

        f32x4 sc[4];
        __builtin_amdgcn_s_setprio(1);
#pragma unroll
        for (int t = 0; t < 4; ++t) {
            sc[t] = (f32x4){0.f, 0.f, 0.f, 0.f};
#pragma unroll
            for (int c = 0; c < 4; ++c) {
                bf16x8 bk = __builtin_bit_cast(bf16x8,
                    *(const uint4*)&Ks[(t * 16 + ln) * 136 + c * 32 + quad * 8]);
                sc[t] = __builtin_amdgcn_mfma_f32_16x16x32_bf16(aq[c], bk, sc[t], 0, 0, 0);
            }
        }
        __builtin_amdgcn_s_setprio(0);

        float alpha[4];
#pragma unroll
        for (int r = 0; r < 4; ++r) {
            float mt = -1e30f;
#pragma unroll
            for (int t = 0; t < 4; ++t) {
                float sv = sc[t][r] * ATTN_SCALE;
                if (kv0 + t * 16 + ln >= kv_end) sv = -1e30f;
                sc[t][r] = sv;
                mt = fmaxf(mt, sv);
            }
#pragma unroll
            for (int mm = 1; mm < 16; mm <<= 1) mt = fmaxf(mt, __shfl_xor(mt, mm, 64));
            const float mn = fmaxf(m_i[r], mt);
            alpha[r] = __expf(m_i[r] - mn);
            m_i[r] = mn;
            float rs = 0.f;
#pragma unroll
            for (int t = 0; t < 4; ++t) {
                const float pv = __expf(sc[t][r] - mn);
                sc[t][r] = pv;
                rs += pv;
            }
#pragma unroll
            for (int mm = 1; mm < 16; mm <<= 1) rs += __shfl_xor(rs, mm, 64);
            l_i[r] = l_i[r] * alpha[r] + rs;
        }

        unsigned short* psw = Ps[wave];
#pragma unroll
        for (int t = 0; t < 4; ++t)
#pragma unroll
            for (int r = 0; r < 4; ++r)
                psw[(quad * 4 + r) * 72 + t * 16 + ln] = f2bf(sc[t][r]);

#pragma unroll
        for (int dt = 0; dt < 8; ++dt)
#pragma unroll
            for (int r = 0; r < 4; ++r) o[dt][r] *= alpha[r];

        bf16x8 ap0 = __builtin_bit_cast(bf16x8, *(const uint4*)&psw[ln * 72 + quad * 8]);
        bf16x8 ap1 = __builtin_bit_cast(bf16x8, *(const uint4*)&psw[ln * 72 + 32 + quad * 8]);
        __builtin_amdgcn_s_setprio(1);
#pragma unroll
        for (int dt = 0; dt < 8; ++dt) {
            bf16x8 bv0 = __builtin_bit_cast(bf16x8,
                *(const uint4*)&Vt[(dt * 16 + ln) * 36 + quad * 4]);
            o[dt] = __builtin_amdgcn_mfma_f32_16x16x32_bf16(ap0, bv0, o[dt], 0, 0, 0);
            bf16x8 bv1 = __builtin_bit_cast(bf16x8,
                *(const uint4*)&Vt[(dt * 16 + ln) * 36 + 16 + quad * 4]);
            o[dt] = __builtin_amdgcn_mfma_f32_16x16x32_bf16(ap1, bv1, o[dt], 0, 0, 0);
        }
        __builtin_amdgcn_s_setprio(0);
    }

    // partial epilogue: UNNORMALIZED o (hi/lo, stride OPS) + m/l at element 128
    const size_t obase = (size_t)(s * NH + h) * NTOT;
#pragma unroll
    for (int r = 0; r < 4; ++r) {
        const int qrow = q0 + wave * 16 + quad * 4 + r;
        if (qrow >= NTOT) continue;
        const size_t row = obase + qrow;
        unsigned short* hp = ophi + row * OPS + ln;
        unsigned short* lp = oplo + row * OPS + ln;
#pragma unroll
        for (int dt = 0; dt < 8; ++dt) {
            const float v = o[dt][r];
            const unsigned int u = __float_as_uint(v);
            hp[dt * 16] = (unsigned short)(u >> 16);
            lp[dt * 16] = f2bf(v - __uint_as_float(u & 0xffff0000u));
        }
        if (ln == 0) {
            *(float*)(ophi + row * OPS + DH) = m_i[r];
            *(float*)(oplo + row * OPS + DH) = l_i[r];
        }
    }
}

// ---------------- combine the 2 kv-split partials, scatter by idx ----------------
__global__ __launch_bounds__(256) void attn_combine_kernel(
    const unsigned short* __restrict__ ophi, const unsigned short* __restrict__ oplo,
    unsigned short* __restrict__ out_hi, unsigned short* __restrict__ out_lo,
    const int* __restrict__ idx)
{
    const int wave = threadIdx.x >> 6, lane = threadIdx.x & 63;
    const int qrow = blockIdx.x * 4 + wave;      // grid.x = NTOT/4 = 562, exact
    const int h = blockIdx.y;
    const size_t r0 = (size_t)h * NTOT + qrow;           // split 0 row
    const size_t r1 = (size_t)(NH + h) * NTOT + qrow;    // split 1 row
    const float m0 = *(const float*)(ophi + r0 * OPS + DH);
    const float l0 = *(const float*)(oplo + r0 * OPS + DH);
    const float m1 = *(const float*)(ophi + r1 * OPS + DH);
    const float l1 = *(const float*)(oplo + r1 * OPS + DH);
    const float m  = fmaxf(m0, m1);
    const float w0 = __expf(m0 - m), w1 = __expf(m1 - m);
    const float inv = 1.f / (l0 * w0 + l1 * w1);

    const ushort2 a0 = *(const ushort2*)(ophi + r0 * OPS + 2 * lane);
    const ushort2 b0 = *(const ushort2*)(oplo + r0 * OPS + 2 * lane);
    const ushort2 a1 = *(const ushort2*)(ophi + r1 * OPS + 2 * lane);
    const ushort2 b1 = *(const ushort2*)(oplo + r1 * OPS + 2 * lane);

    float vx = ((bf2f(a0.x) + bf2f(b0.x)) * w0 + (bf2f(a1.x) + bf2f(b1.x)) * w1) * inv;
    float vy = ((bf2f(a0.y) + bf2f(b0.y)) * w0 + (bf2f(a1.y) + bf2f(b1.y)) * w1) * inv;

    ushort2 oh, ol;
    const unsigned int ux = __float_as_uint(vx);
    oh.x = (unsigned short)(ux >> 16);
    ol.x = f2bf(vx - __uint_as_float(ux & 0xffff0000u));
    const unsigned int uy = __float_as_uint(vy);
    oh.y = (unsigned short)(uy >> 16);
    ol.y = f2bf(vy - __uint_as_float(uy & 0xffff0000u));

    const size_t doff = (size_t)idx[qrow] * DXC + h * DH + 2 * lane;
    *(ushort2*)(out_hi + doff) = oh;
    *(ushort2*)(out_lo + doff) = ol;
}

extern "C" void kernel_launch(void* const* d_in, const int* in_sizes, int n_in,
                              void* d_out, int out_size, void* d_ws, size_t ws_size,
                              hipStream_t stream)
{
    const float* x        = (const float*)d_in[0];
    const float* y        = (const float*)d_in[1];
    const float* scale_x  = (const float*)d_in[2];
    const float* scale_y  = (const float*)d_in[3];
    const float* rope_cos = (const float*)d_in[4];
    const float* rope_sin = (const float*)d_in[5];
    const float* W_qkv_x  = (const float*)d_in[6];
    const float* b_qkv_x  = (const float*)d_in[7];
    const float* W_qkv_y  = (const float*)d_in[8];
    const float* b_qkv_y  = (const float*)d_in[9];
    const float* q_norm_x = (const float*)d_in[10];
    const float* k_norm_x = (const float*)d_in[11];
    const float* q_norm_y = (const float*)d_in[12];
    const float* k_norm_y = (const float*)d_in[13];
    const float* W_proj_x = (const float*)d_in[14];
    const float* b_proj_x = (const float*)d_in[15];
    const float* W_proj_y = (const float*)d_in[16];
    const float* b_proj_y = (const float*)d_in[17];
    const int*   vidx     = (const int*)d_in[18];
    float* out = (float*)d_out;

    unsigned short* wsu = (unsigned short*)d_ws;
    const size_t SEG = (size_t)NLTOK * DXC;   // 7,077,888 elements
    unsigned short* q16     = wsu;
    unsigned short* k16     = wsu + SEG;
    unsigned short* v16     = wsu + 2 * SEG;
    unsigned short* xm_hi   = wsu + 5 * SEG;
    unsigned short* xm_lo   = wsu + 6 * SEG;
    unsigned short* ym_hi   = xm_hi + (size_t)NX * DXC;  // fits in SEG slack
    unsigned short* ym_lo   = xm_lo + (size_t)NX * DXC;
    // attn partials: each buffer = 2*NH*NTOT rows * stride 130 = 14,027,520
    // ushorts (~2 SEG). opart_hi spans segs 3-4; opart_lo spans segs 5-6
    // (xm/ym, dead after QKV GEMMs). In-bounds within 7*SEG.
    unsigned short* opart_hi = wsu + 3 * SEG;
    unsigned short* opart_lo = wsu + 5 * SEG;
    // final attn output (combine target, proj-GEMM A): q16/k16, dead after attn.
    unsigned short* fin_hi = q16;
    unsigned short* fin_lo = k16;

    // 1) rmsnorm * (1 + scale), pre-split hi/lo
    rmsnorm_scale_split_kernel<<<NX, 256, 0, stream>>>(x, scale_x, xm_hi, xm_lo, DXC);
    rmsnorm_scale_split_kernel<<<LY, 256, 0, stream>>>(y, scale_y, ym_hi, ym_lo, DYC);

    // 2) QKV GEMMs fused into ONE dispatch: y-rows 0-15 = x-problem (2048x9216
    //    K=3072), rows 16-17 = y-problem (256x9216 K=1536). Scatter to q/k/v.
    gemm_split_dual_kernel<<<dim3(9216 / 128, NX / 128 + LY / 128), 256, 0, stream>>>(
        xm_hi, xm_lo, W_qkv_x, b_qkv_x, nullptr, q16, k16, v16, 0, DXC, 1, 0,
        ym_hi, ym_lo, W_qkv_y, b_qkv_y, nullptr, 0, DYC, 1, NX,
        NX / 128, 9216 / 128);

    // 3) per-head q/k rmsnorm (+rope for x tokens)
    qknorm_rope_kernel<<<NLTOK * NH * 2, 128, 0, stream>>>(
        q16, k16, q_norm_x, k_norm_x, q_norm_y, k_norm_y, rope_cos, rope_sin);

    // 4) flash attention, 2-way KV split -> partials
    attn_kernel<<<dim3(NH * NQT, 2), 256, 0, stream>>>(
        q16, k16, v16, opart_hi, opart_lo, vidx);

    // 4b) zero the combine scatter target (q16+k16 contiguous; q/k dead now),
    //     then combine partials -> fin (rows not in idx stay zero for proj)
    hipMemsetAsync(fin_hi, 0, 2 * SEG * sizeof(unsigned short), stream);
    attn_combine_kernel<<<dim3(NTOT / 4, NH), 256, 0, stream>>>(
        opart_hi, opart_lo, fin_hi, fin_lo, vidx);

    // 5) output projections fused into ONE dispatch: rows 0-15 = x-proj
    //    (2048x3072), rows 16-17 = y-proj (256x1536, 12 n-blocks).
    gemm_split_dual_kernel<<<dim3(DXC / 128, NX / 128 + LY / 128), 256, 0, stream>>>(
        fin_hi, fin_lo, W_proj_x, b_proj_x, out, nullptr, nullptr, nullptr,
        DXC, DXC, 0, 0,
        fin_hi + (size_t)NX * DXC, fin_lo + (size_t)NX * DXC,
        W_proj_y, b_proj_y, out + (size_t)NX * DXC,
        DYC, DXC, 0, 0,
        NX / 128, DYC / 128);
}